// Round 5
// baseline (669.571 us; speedup 1.0000x reference)
//
#include <hip/hip_runtime.h>

typedef unsigned short u16;
typedef __attribute__((ext_vector_type(8))) __bf16 bf16x8;
typedef __attribute__((ext_vector_type(4))) float f32x4;

#define TSEQ 2048
#define NBATCH 4
#define NHEAD 16
#define HDIM 64
#define CDIM 1024
// 1/sqrt(64) * log2(e): folds attn scale + exp->exp2 conversion into Q
#define QSCALE 0.18033688011112042f

__device__ __forceinline__ u16 f2bf(float f) {
  unsigned u = __float_as_uint(f);
  u += 0x7fffu + ((u >> 16) & 1u);   // round-to-nearest-even
  return (u16)(u >> 16);
}
__device__ __forceinline__ float bf2f(u16 s) {
  return __uint_as_float(((unsigned)s) << 16);
}

__device__ __forceinline__ f32x4 mfma_bf16(bf16x8 a, bf16x8 b, f32x4 c) {
  return __builtin_amdgcn_mfma_f32_16x16x32_bf16(a, b, c, 0, 0, 0);
}

// async global->LDS, 16B per lane. LDS dest is wave-uniform base + lane*16.
__device__ __forceinline__ void async16(const u16* g, u16* l) {
  __builtin_amdgcn_global_load_lds(
      (__attribute__((address_space(1))) unsigned int*)g,
      (__attribute__((address_space(3))) unsigned int*)l, 16, 0, 0);
}

// ---------------- fp32 -> bf16 convert ----------------
__global__ __launch_bounds__(256) void cvt_bf16(const float* __restrict__ in,
                                                u16* __restrict__ out, int n) {
  int i = (blockIdx.x * 256 + threadIdx.x) * 4;
  if (i >= n) return;
  float4 v = *reinterpret_cast<const float4*>(in + i);
  ushort4 o;
  o.x = f2bf(v.x); o.y = f2bf(v.y); o.z = f2bf(v.z); o.w = f2bf(v.w);
  *reinterpret_cast<ushort4*>(out + i) = o;
}

// 4 weight matrices in one dispatch; blockIdx.y selects
__global__ __launch_bounds__(256) void cvt_w4(const float* __restrict__ w0,
                                              const float* __restrict__ w1,
                                              const float* __restrict__ w2,
                                              const float* __restrict__ w3,
                                              u16* __restrict__ out) {
  const float* src = blockIdx.y == 0 ? w0 : blockIdx.y == 1 ? w1
                    : blockIdx.y == 2 ? w2 : w3;
  u16* dst = out + (size_t)blockIdx.y * CDIM * CDIM;
  int i = (blockIdx.x * 256 + threadIdx.x) * 4;
  float4 v = *reinterpret_cast<const float4*>(src + i);
  ushort4 o;
  o.x = f2bf(v.x); o.y = f2bf(v.y); o.z = f2bf(v.z); o.w = f2bf(v.w);
  *reinterpret_cast<ushort4*>(dst + i) = o;
}

// ---------------- RoPE + RMSNorm (in place, bf16), Q and K in one dispatch ----
// one wave per (b,t,h) row of 64; lane = d; blockIdx.y: 0=Q (scaled), 1=K
__global__ __launch_bounds__(256) void rope_rms2(u16* __restrict__ Q,
                                                 u16* __restrict__ K,
                                                 const float* __restrict__ cp,
                                                 const float* __restrict__ sp) {
  u16* qk = blockIdx.y == 0 ? Q : K;
  float scale = blockIdx.y == 0 ? QSCALE : 1.0f;
  int lane = threadIdx.x & 63;
  int rid = blockIdx.x * 4 + (threadIdx.x >> 6);   // (b*T + t)*H + h
  int t = (rid >> 4) & (TSEQ - 1);
  size_t off = (size_t)rid * HDIM + lane;
  float q = bf2f(qk[off]);
  float partner = __shfl_xor(q, 32);
  float rot = (lane < 32) ? -partner : partner;    // rotate_half
  float y = q * cp[t * HDIM + lane] + rot * sp[t * HDIM + lane];
  float ss = y * y;
  #pragma unroll
  for (int o = 1; o < 64; o <<= 1) ss += __shfl_xor(ss, o);
  float r = rsqrtf(ss * (1.0f / 64.0f) + 1e-6f);
  qk[off] = f2bf(y * r * scale);
}

// ---------------- GEMM core: C[m][n] = sum_k A[m][k] * Bt[n][k] ----------------
// 128x128 tile, BK=32, 256 threads = 4 waves (2x2), m97 structure.
// MODE: 0 = bf16 row-major out, 1 = f32 row-major out, 2 = V-transposed out
template <int MODE>
__device__ __forceinline__ void gemm_core(const u16* __restrict__ A,
                                          const u16* __restrict__ Bt,
                                          void* __restrict__ Cv,
                                          int bx, int by, int N, int K) {
  __shared__ __align__(16) u16 As[128 * 32];
  __shared__ __align__(16) u16 Bs[128 * 32];
  const int lane = threadIdx.x & 63;
  const int w = threadIdx.x >> 6;
  const int f = lane & 15, g = lane >> 4;
  const int wr = w >> 1, wc = w & 1;
  const size_t brow = (size_t)bx * 128;
  const size_t bcol = (size_t)by * 128;
  const int ar = lane >> 2;          // row within 16-row chunk
  const int ac = (lane & 3) * 8;     // col (elements)
  f32x4 acc[4][4] = {};
  for (int k0 = 0; k0 < K; k0 += 32) {
    #pragma unroll
    for (int i = 0; i < 2; ++i) {
      const int c = w + i * 4;       // chunk 0..7 (16 rows each)
      async16(A + (brow + c * 16 + ar) * (size_t)K + (k0 + ac), &As[c * 512]);
      async16(Bt + (bcol + c * 16 + ar) * (size_t)K + (k0 + ac), &Bs[c * 512]);
    }
    __syncthreads();                 // drains vmcnt before barrier
    bf16x8 a[4], b[4];
    #pragma unroll
    for (int m = 0; m < 4; ++m)
      a[m] = *reinterpret_cast<const bf16x8*>(&As[(wr * 64 + m * 16 + f) * 32 + g * 8]);
    #pragma unroll
    for (int n = 0; n < 4; ++n)
      b[n] = *reinterpret_cast<const bf16x8*>(&Bs[(wc * 64 + n * 16 + f) * 32 + g * 8]);
    #pragma unroll
    for (int m = 0; m < 4; ++m)
      #pragma unroll
      for (int n = 0; n < 4; ++n)
        acc[m][n] = mfma_bf16(a[m], b[n], acc[m][n]);
    __syncthreads();
  }
  // epilogue: D row = (lane>>4)*4 + j, col = lane&15 (m89-verified layout)
  #pragma unroll
  for (int m = 0; m < 4; ++m)
    #pragma unroll
    for (int n = 0; n < 4; ++n) {
      size_t row0 = brow + wr * 64 + m * 16 + g * 4;   // j adds 0..3
      size_t col  = bcol + wc * 64 + n * 16 + f;
      if constexpr (MODE == 0) {
        #pragma unroll
        for (int j = 0; j < 4; ++j)
          reinterpret_cast<u16*>(Cv)[(row0 + j) * (size_t)N + col] = f2bf(acc[m][n][j]);
      } else if constexpr (MODE == 1) {
        #pragma unroll
        for (int j = 0; j < 4; ++j)
          reinterpret_cast<float*>(Cv)[(row0 + j) * (size_t)N + col] = acc[m][n][j];
      } else {
        // V transposed: Vt[((b*H + h)*D + d)][t]; row = b*T + t, col = h*D + d
        int bh = (int)(row0 >> 11) * NHEAD + (int)(col >> 6);
        size_t t0 = row0 & (TSEQ - 1);               // 4-aligned
        ushort4 o4;
        o4.x = f2bf(acc[m][n][0]); o4.y = f2bf(acc[m][n][1]);
        o4.z = f2bf(acc[m][n][2]); o4.w = f2bf(acc[m][n][3]);
        *reinterpret_cast<ushort4*>(
            reinterpret_cast<u16*>(Cv) + ((size_t)bh * HDIM + (col & 63)) * TSEQ + t0) = o4;
      }
    }
}

// fused QKV projection: grid (64, 24); y>>3 selects Q/K/V, V written transposed
__global__ __launch_bounds__(256) void gemm_qkv(const u16* __restrict__ A,
                                                const u16* __restrict__ Wq,
                                                const u16* __restrict__ Wk,
                                                const u16* __restrict__ Wv,
                                                u16* __restrict__ Q,
                                                u16* __restrict__ Kk,
                                                u16* __restrict__ Vt) {
  int sel = blockIdx.y >> 3;
  int by = blockIdx.y & 7;
  if (sel == 0)      gemm_core<0>(A, Wq, Q,  blockIdx.x, by, CDIM, CDIM);
  else if (sel == 1) gemm_core<0>(A, Wk, Kk, blockIdx.x, by, CDIM, CDIM);
  else               gemm_core<2>(A, Wv, Vt, blockIdx.x, by, CDIM, CDIM);
}

__global__ __launch_bounds__(256) void gemm_out(const u16* __restrict__ A,
                                                const u16* __restrict__ Bt,
                                                float* __restrict__ C) {
  gemm_core<1>(A, Bt, C, blockIdx.x, blockIdx.y, CDIM, CDIM);
}

// ---------------- flash attention ----------------
// grid 2048 flat (XCD-swizzled); 256 threads = 4 waves; wave w owns 16 q rows.
// Q is pre-scaled by 0.125*log2(e); softmax runs in log2 domain via exp2f.
__global__ __launch_bounds__(256, 4) void attn(const u16* __restrict__ Q,
                                               const u16* __restrict__ K,
                                               const u16* __restrict__ Vt,
                                               u16* __restrict__ Y) {
  __shared__ __align__(16) u16 P[4][16 * 128];   // per-wave P tile, XOR-swizzled
  // bijective XCD swizzle (2048 % 8 == 0): contiguous wgid chunk per XCD
  const int wgid = (blockIdx.x & 7) * 256 + (blockIdx.x >> 3);
  const int bx = wgid & 31;          // q-tile (T/64 = 32)
  const int by = wgid >> 5;          // (b,h)  (64)
  const int lane = threadIdx.x & 63;
  const int w = threadIdx.x >> 6;
  const int f = lane & 15, g = lane >> 4;
  const int b = by >> 4, h = by & 15;
  const size_t base = ((size_t)b * TSEQ) * CDIM + h * HDIM;
  const u16* Vb = Vt + (size_t)by * HDIM * TSEQ;   // [d][t] for this (b,h)
  const int q0 = bx * 64 + w * 16;
  u16* Pw = P[w];

  // Q A-frags hoisted to registers (contiguous 16B global loads)
  bf16x8 aq[2];
  #pragma unroll
  for (int kq = 0; kq < 2; ++kq)
    aq[kq] = *reinterpret_cast<const bf16x8*>(
        Q + base + (size_t)(q0 + f) * CDIM + kq * 32 + g * 8);

  float mrun[4], lrun[4];
  f32x4 o[4] = {};
  #pragma unroll
  for (int j = 0; j < 4; ++j) { mrun[j] = -1e30f; lrun[j] = 0.f; }

  for (int kt = 0; kt < TSEQ; kt += 128) {
    // ---- S = Q K^T (K B-frags straight from global/L2); S in log2 units ----
    f32x4 sa[8] = {};
    #pragma unroll
    for (int nf = 0; nf < 8; ++nf) {
      const u16* kp = K + base + (size_t)(kt + nf * 16 + f) * CDIM;
      bf16x8 bk0 = *reinterpret_cast<const bf16x8*>(kp + g * 8);
      bf16x8 bk1 = *reinterpret_cast<const bf16x8*>(kp + 32 + g * 8);
      sa[nf] = mfma_bf16(aq[1], bk1, mfma_bf16(aq[0], bk0, sa[nf]));
    }

    // ---- online softmax (row = g*4 + j, col = nf*16 + f) ----
    float vmax[4];
    bool ok = true;
    #pragma unroll
    for (int j = 0; j < 4; ++j) {
      float v = sa[0][j];
      #pragma unroll
      for (int nf = 1; nf < 8; ++nf) v = fmaxf(v, sa[nf][j]);
      #pragma unroll
      for (int off = 1; off < 16; off <<= 1) v = fmaxf(v, __shfl_xor(v, off));
      vmax[j] = v;
      ok = ok && (v - mrun[j] <= 8.0f);
    }
    if (!__all(ok)) {                 // T13 defer-max: rescale only when needed
      #pragma unroll
      for (int j = 0; j < 4; ++j) {
        float mn = fmaxf(mrun[j], vmax[j]);
        float sf = __builtin_exp2f(mrun[j] - mn);
        mrun[j] = mn;
        lrun[j] *= sf;
        #pragma unroll
        for (int nfo = 0; nfo < 4; ++nfo) o[nfo][j] *= sf;
      }
    }
    float psum[4] = {};
    #pragma unroll
    for (int nf = 0; nf < 8; ++nf)
      #pragma unroll
      for (int j = 0; j < 4; ++j) {
        float p = __builtin_exp2f(sa[nf][j] - mrun[j]);
        psum[j] += p;
        int row = g * 4 + j;
        int col = nf * 16 + f;
        Pw[row * 128 + (col ^ ((row & 7) << 3))] = f2bf(p);
      }
    #pragma unroll
    for (int j = 0; j < 4; ++j) {
      float s = psum[j];
      #pragma unroll
      for (int off = 1; off < 16; off <<= 1) s += __shfl_xor(s, off);
      lrun[j] += s;
    }

    // ---- O += P V  (P A-frags from per-wave LDS; V B-frags 16B from Vt) ----
    #pragma unroll
    for (int ks = 0; ks < 4; ++ks) {
      bf16x8 pa = *reinterpret_cast<const bf16x8*>(
          &Pw[f * 128 + ((ks * 32 + g * 8) ^ ((f & 7) << 3))]);
      #pragma unroll
      for (int nfo = 0; nfo < 4; ++nfo) {
        bf16x8 bv = *reinterpret_cast<const bf16x8*>(
            Vb + (size_t)(nfo * 16 + f) * TSEQ + kt + ks * 32 + g * 8);
        o[nfo] = mfma_bf16(pa, bv, o[nfo]);
      }
    }
  }

  // ---- epilogue: Y = O / l ----
  #pragma unroll
  for (int j = 0; j < 4; ++j) {
    float rcp = 1.0f / lrun[j];
    #pragma unroll
    for (int nfo = 0; nfo < 4; ++nfo) {
      float val = o[nfo][j] * rcp;
      Y[base + (size_t)(q0 + g * 4 + j) * CDIM + nfo * 16 + f] = f2bf(val);
    }
  }
}

extern "C" void kernel_launch(void* const* d_in, const int* in_sizes, int n_in,
                              void* d_out, int out_size, void* d_ws, size_t ws_size,
                              hipStream_t stream) {
  const float* x  = (const float*)d_in[0];
  const float* cp = (const float*)d_in[1];
  const float* sp = (const float*)d_in[2];
  const float* Wq = (const float*)d_in[3];
  const float* Wk = (const float*)d_in[4];
  const float* Wv = (const float*)d_in[5];
  const float* Wo = (const float*)d_in[6];
  float* out = (float*)d_out;

  const int NX = NBATCH * TSEQ * CDIM;   // 8388608
  const int NW = CDIM * CDIM;            // 1048576

  // ws layout (needs 42 MB): xb/Yb | Vt | Wqb Wkb Wvb Wob
  u16* xb  = (u16*)d_ws;           // also reused as Y after QKV GEMMs
  u16* Vt  = xb + NX;              // [b][h][d][t] transposed V
  u16* Wqb = Vt + NX;
  u16* Wkb = Wqb + NW;
  u16* Wvb = Wkb + NW;
  u16* Wob = Wvb + NW;
  // Q,K live in d_out (2 * 16.8MB bf16 == 33.6MB fp32) until the final GEMM
  u16* Qb = (u16*)d_out;
  u16* Kb = Qb + NX;

  cvt_bf16<<<NX / 1024, 256, 0, stream>>>(x, xb, NX);
  cvt_w4<<<dim3(NW / 1024, 4), 256, 0, stream>>>(Wq, Wk, Wv, Wo, Wqb);

  dim3 gq(NBATCH * TSEQ / 128, 24);           // fused Q|K|V
  gemm_qkv<<<gq, 256, 0, stream>>>(xb, Wqb, Wkb, Wvb, Qb, Kb, Vt);

  rope_rms2<<<dim3(NBATCH * TSEQ * NHEAD / 4, 2), 256, 0, stream>>>(Qb, Kb, cp, sp);

  attn<<<2048, 256, 0, stream>>>(Qb, Kb, Vt, xb);

  dim3 gg(NBATCH * TSEQ / 128, CDIM / 128);   // (64, 8)
  gemm_out<<<gg, 256, 0, stream>>>(xb, Wob, out);
}

// Round 6
// 396.025 us; speedup vs baseline: 1.6907x; 1.6907x over previous
//
#include <hip/hip_runtime.h>

typedef unsigned short u16;
typedef __attribute__((ext_vector_type(8))) __bf16 bf16x8;
typedef __attribute__((ext_vector_type(4))) float f32x4;

#define TSEQ 2048
#define NBATCH 4
#define NHEAD 16
#define HDIM 64
#define CDIM 1024
// 1/sqrt(64) * log2(e): folds attn scale + exp->exp2 conversion into Q
#define QSCALE 0.18033688011112042f

__device__ __forceinline__ u16 f2bf(float f) {
  unsigned u = __float_as_uint(f);
  u += 0x7fffu + ((u >> 16) & 1u);   // round-to-nearest-even
  return (u16)(u >> 16);
}
__device__ __forceinline__ float bf2f(u16 s) {
  return __uint_as_float(((unsigned)s) << 16);
}

__device__ __forceinline__ f32x4 mfma_bf16(bf16x8 a, bf16x8 b, f32x4 c) {
  return __builtin_amdgcn_mfma_f32_16x16x32_bf16(a, b, c, 0, 0, 0);
}

// async global->LDS, 16B per lane. LDS dest is wave-uniform base + lane*16.
__device__ __forceinline__ void async16(const u16* g, u16* l) {
  __builtin_amdgcn_global_load_lds(
      (__attribute__((address_space(1))) unsigned int*)g,
      (__attribute__((address_space(3))) unsigned int*)l, 16, 0, 0);
}

// ---------------- fp32 -> bf16 convert ----------------
__global__ __launch_bounds__(256) void cvt_bf16(const float* __restrict__ in,
                                                u16* __restrict__ out, int n) {
  int i = (blockIdx.x * 256 + threadIdx.x) * 4;
  if (i >= n) return;
  float4 v = *reinterpret_cast<const float4*>(in + i);
  ushort4 o;
  o.x = f2bf(v.x); o.y = f2bf(v.y); o.z = f2bf(v.z); o.w = f2bf(v.w);
  *reinterpret_cast<ushort4*>(out + i) = o;
}

// 4 weight matrices in one dispatch; blockIdx.y selects
__global__ __launch_bounds__(256) void cvt_w4(const float* __restrict__ w0,
                                              const float* __restrict__ w1,
                                              const float* __restrict__ w2,
                                              const float* __restrict__ w3,
                                              u16* __restrict__ out) {
  const float* src = blockIdx.y == 0 ? w0 : blockIdx.y == 1 ? w1
                    : blockIdx.y == 2 ? w2 : w3;
  u16* dst = out + (size_t)blockIdx.y * CDIM * CDIM;
  int i = (blockIdx.x * 256 + threadIdx.x) * 4;
  float4 v = *reinterpret_cast<const float4*>(src + i);
  ushort4 o;
  o.x = f2bf(v.x); o.y = f2bf(v.y); o.z = f2bf(v.z); o.w = f2bf(v.w);
  *reinterpret_cast<ushort4*>(dst + i) = o;
}

// ---------------- RoPE + RMSNorm (in place, bf16), Q and K in one dispatch ----
// one wave per (b,t,h) row of 64; lane = d; blockIdx.y: 0=Q (scaled), 1=K
__global__ __launch_bounds__(256) void rope_rms2(u16* __restrict__ Q,
                                                 u16* __restrict__ K,
                                                 const float* __restrict__ cp,
                                                 const float* __restrict__ sp) {
  u16* qk = blockIdx.y == 0 ? Q : K;
  float scale = blockIdx.y == 0 ? QSCALE : 1.0f;
  int lane = threadIdx.x & 63;
  int rid = blockIdx.x * 4 + (threadIdx.x >> 6);   // (b*T + t)*H + h
  int t = (rid >> 4) & (TSEQ - 1);
  size_t off = (size_t)rid * HDIM + lane;
  float q = bf2f(qk[off]);
  float partner = __shfl_xor(q, 32);
  float rot = (lane < 32) ? -partner : partner;    // rotate_half
  float y = q * cp[t * HDIM + lane] + rot * sp[t * HDIM + lane];
  float ss = y * y;
  #pragma unroll
  for (int o = 1; o < 64; o <<= 1) ss += __shfl_xor(ss, o);
  float r = rsqrtf(ss * (1.0f / 64.0f) + 1e-6f);
  qk[off] = f2bf(y * r * scale);
}

// ---------------- GEMM core: C[m][n] = sum_k A[m][k] * Bt[n][k] ----------------
// 128x128 tile, BK=32, 256 threads = 4 waves (2x2), m97 structure.
// MODE: 0 = bf16 row-major out, 1 = f32 row-major out, 2 = V-transposed out
template <int MODE>
__device__ __forceinline__ void gemm_core(const u16* __restrict__ A,
                                          const u16* __restrict__ Bt,
                                          void* __restrict__ Cv,
                                          int bx, int by, int N, int K) {
  __shared__ __align__(16) u16 As[128 * 32];
  __shared__ __align__(16) u16 Bs[128 * 32];
  const int lane = threadIdx.x & 63;
  const int w = threadIdx.x >> 6;
  const int f = lane & 15, g = lane >> 4;
  const int wr = w >> 1, wc = w & 1;
  const size_t brow = (size_t)bx * 128;
  const size_t bcol = (size_t)by * 128;
  const int ar = lane >> 2;          // row within 16-row chunk
  const int ac = (lane & 3) * 8;     // col (elements)
  f32x4 acc[4][4] = {};
  for (int k0 = 0; k0 < K; k0 += 32) {
    #pragma unroll
    for (int i = 0; i < 2; ++i) {
      const int c = w + i * 4;       // chunk 0..7 (16 rows each)
      async16(A + (brow + c * 16 + ar) * (size_t)K + (k0 + ac), &As[c * 512]);
      async16(Bt + (bcol + c * 16 + ar) * (size_t)K + (k0 + ac), &Bs[c * 512]);
    }
    __syncthreads();                 // drains vmcnt before barrier
    bf16x8 a[4], b[4];
    #pragma unroll
    for (int m = 0; m < 4; ++m)
      a[m] = *reinterpret_cast<const bf16x8*>(&As[(wr * 64 + m * 16 + f) * 32 + g * 8]);
    #pragma unroll
    for (int n = 0; n < 4; ++n)
      b[n] = *reinterpret_cast<const bf16x8*>(&Bs[(wc * 64 + n * 16 + f) * 32 + g * 8]);
    #pragma unroll
    for (int m = 0; m < 4; ++m)
      #pragma unroll
      for (int n = 0; n < 4; ++n)
        acc[m][n] = mfma_bf16(a[m], b[n], acc[m][n]);
    __syncthreads();
  }
  // epilogue: D row = (lane>>4)*4 + j, col = lane&15 (m89-verified layout)
  #pragma unroll
  for (int m = 0; m < 4; ++m)
    #pragma unroll
    for (int n = 0; n < 4; ++n) {
      size_t row0 = brow + wr * 64 + m * 16 + g * 4;   // j adds 0..3
      size_t col  = bcol + wc * 64 + n * 16 + f;
      if constexpr (MODE == 0) {
        #pragma unroll
        for (int j = 0; j < 4; ++j)
          reinterpret_cast<u16*>(Cv)[(row0 + j) * (size_t)N + col] = f2bf(acc[m][n][j]);
      } else if constexpr (MODE == 1) {
        #pragma unroll
        for (int j = 0; j < 4; ++j)
          reinterpret_cast<float*>(Cv)[(row0 + j) * (size_t)N + col] = acc[m][n][j];
      } else {
        // V transposed: Vt[((b*H + h)*D + d)][t]; row = b*T + t, col = h*D + d
        int bh = (int)(row0 >> 11) * NHEAD + (int)(col >> 6);
        size_t t0 = row0 & (TSEQ - 1);               // 4-aligned
        ushort4 o4;
        o4.x = f2bf(acc[m][n][0]); o4.y = f2bf(acc[m][n][1]);
        o4.z = f2bf(acc[m][n][2]); o4.w = f2bf(acc[m][n][3]);
        *reinterpret_cast<ushort4*>(
            reinterpret_cast<u16*>(Cv) + ((size_t)bh * HDIM + (col & 63)) * TSEQ + t0) = o4;
      }
    }
}

// fused QKV projection: grid (64, 24); y>>3 selects Q/K/V, V written transposed
__global__ __launch_bounds__(256) void gemm_qkv(const u16* __restrict__ A,
                                                const u16* __restrict__ Wq,
                                                const u16* __restrict__ Wk,
                                                const u16* __restrict__ Wv,
                                                u16* __restrict__ Q,
                                                u16* __restrict__ Kk,
                                                u16* __restrict__ Vt) {
  int sel = blockIdx.y >> 3;
  int by = blockIdx.y & 7;
  if (sel == 0)      gemm_core<0>(A, Wq, Q,  blockIdx.x, by, CDIM, CDIM);
  else if (sel == 1) gemm_core<0>(A, Wk, Kk, blockIdx.x, by, CDIM, CDIM);
  else               gemm_core<2>(A, Wv, Vt, blockIdx.x, by, CDIM, CDIM);
}

__global__ __launch_bounds__(256) void gemm_out(const u16* __restrict__ A,
                                                const u16* __restrict__ Bt,
                                                float* __restrict__ C) {
  gemm_core<1>(A, Bt, C, blockIdx.x, blockIdx.y, CDIM, CDIM);
}

// ---------------- flash attention ----------------
// grid 2048 flat (XCD-swizzled); 256 threads = 4 waves; wave w owns 16 q rows.
// K/V tiles staged block-cooperatively into LDS via global_load_lds (m97
// structure); T2 XOR-swizzle applied via pre-swizzled global source (m173).
// Q is pre-scaled by 0.125*log2(e); softmax runs in log2 domain via exp2f.
__global__ __launch_bounds__(256, 3) void attn(const u16* __restrict__ Q,
                                               const u16* __restrict__ K,
                                               const u16* __restrict__ Vt,
                                               u16* __restrict__ Y) {
  // LDS element (r,d) of K tile lives at u16 addr r*64 + (d ^ ((r&7)<<3))
  __shared__ __align__(16) u16 Ks[128 * 64];     // 16 KB: [kv 128][d 64]
  // LDS element (d,t) of V tile lives at u16 addr d*128 + (t ^ ((d&7)<<3))
  __shared__ __align__(16) u16 Vs[64 * 128];     // 16 KB: [d 64][t 128]
  __shared__ __align__(16) u16 P[4][16 * 128];   // per-wave P tile, XOR-swizzled
  // bijective XCD swizzle (2048 % 8 == 0): contiguous wgid chunk per XCD
  const int wgid = (blockIdx.x & 7) * 256 + (blockIdx.x >> 3);
  const int bx = wgid & 31;          // q-tile (T/64 = 32)
  const int by = wgid >> 5;          // (b,h)  (64)
  const int lane = threadIdx.x & 63;
  const int w = threadIdx.x >> 6;
  const int f = lane & 15, g = lane >> 4;
  const int b = by >> 4, h = by & 15;
  const size_t base = ((size_t)b * TSEQ) * CDIM + h * HDIM;
  const u16* Kg = K + base;                        // row stride CDIM
  const u16* Vg = Vt + (size_t)by * HDIM * TSEQ;   // [d][t], row stride TSEQ
  const int q0 = bx * 64 + w * 16;
  u16* Pw = P[w];

  // staging lane coords (computed once)
  const int kl8 = lane >> 3, kl7 = lane & 7;
  const int kswz = 8 * (kl7 ^ kl8);                // K src d-offset (u16)
  const int vl16 = lane >> 4, vl15 = lane & 15;

  // Q A-frags hoisted to registers (contiguous 16B global loads)
  bf16x8 aq[2];
  #pragma unroll
  for (int kq = 0; kq < 2; ++kq)
    aq[kq] = *reinterpret_cast<const bf16x8*>(
        Q + base + (size_t)(q0 + f) * CDIM + kq * 32 + g * 8);

  // prologue: stage tile 0
  #pragma unroll
  for (int i = 0; i < 4; ++i) {
    int c = w * 4 + i;
    async16(Kg + (size_t)(c * 8 + kl8) * CDIM + kswz, &Ks[c * 512]);
    int r7 = ((c & 1) << 2) + vl16;                // (4c + l>>4) & 7
    async16(Vg + (size_t)(c * 4 + vl16) * TSEQ + 8 * (vl15 ^ r7), &Vs[c * 512]);
  }
  __syncthreads();

  float mrun[4], lrun[4];
  f32x4 o[4] = {};
  #pragma unroll
  for (int j = 0; j < 4; ++j) { mrun[j] = -1e30f; lrun[j] = 0.f; }

  for (int kt = 0; kt < TSEQ; kt += 128) {
    // ---- S = Q K^T (K B-frags from swizzled LDS); S in log2 units ----
    f32x4 sa[8] = {};
    #pragma unroll
    for (int nf = 0; nf < 8; ++nf) {
      const u16* kp = &Ks[(nf * 16 + f) * 64];
      bf16x8 bk0 = *reinterpret_cast<const bf16x8*>(kp + ((g * 8) ^ ((f & 7) << 3)));
      bf16x8 bk1 = *reinterpret_cast<const bf16x8*>(kp + ((32 + g * 8) ^ ((f & 7) << 3)));
      sa[nf] = mfma_bf16(aq[1], bk1, mfma_bf16(aq[0], bk0, sa[nf]));
    }

    // ---- online softmax (row = g*4 + j, col = nf*16 + f) ----
    float vmax[4];
    bool ok = true;
    #pragma unroll
    for (int j = 0; j < 4; ++j) {
      float v = sa[0][j];
      #pragma unroll
      for (int nf = 1; nf < 8; ++nf) v = fmaxf(v, sa[nf][j]);
      #pragma unroll
      for (int off = 1; off < 16; off <<= 1) v = fmaxf(v, __shfl_xor(v, off));
      vmax[j] = v;
      ok = ok && (v - mrun[j] <= 8.0f);
    }
    if (!__all(ok)) {                 // T13 defer-max: rescale only when needed
      #pragma unroll
      for (int j = 0; j < 4; ++j) {
        float mn = fmaxf(mrun[j], vmax[j]);
        float sf = __builtin_exp2f(mrun[j] - mn);
        mrun[j] = mn;
        lrun[j] *= sf;
        #pragma unroll
        for (int nfo = 0; nfo < 4; ++nfo) o[nfo][j] *= sf;
      }
    }
    float psum[4] = {};
    #pragma unroll
    for (int nf = 0; nf < 8; ++nf)
      #pragma unroll
      for (int j = 0; j < 4; ++j) {
        float p = __builtin_exp2f(sa[nf][j] - mrun[j]);
        psum[j] += p;
        int row = g * 4 + j;
        int col = nf * 16 + f;
        Pw[row * 128 + (col ^ ((row & 7) << 3))] = f2bf(p);
      }
    #pragma unroll
    for (int j = 0; j < 4; ++j) {
      float s = psum[j];
      #pragma unroll
      for (int off = 1; off < 16; off <<= 1) s += __shfl_xor(s, off);
      lrun[j] += s;
    }

    // ---- O += P V  (P A-frags + V B-frags from swizzled LDS) ----
    #pragma unroll
    for (int ks = 0; ks < 4; ++ks) {
      bf16x8 pa = *reinterpret_cast<const bf16x8*>(
          &Pw[f * 128 + ((ks * 32 + g * 8) ^ ((f & 7) << 3))]);
      #pragma unroll
      for (int nfo = 0; nfo < 4; ++nfo) {
        bf16x8 bv = *reinterpret_cast<const bf16x8*>(
            &Vs[(nfo * 16 + f) * 128 + ((ks * 32 + g * 8) ^ ((f & 7) << 3))]);
        o[nfo] = mfma_bf16(pa, bv, o[nfo]);
      }
    }

    // ---- stage next tile (single-buffered: fence both sides) ----
    __syncthreads();                 // all waves done reading Ks/Vs
    if (kt + 128 < TSEQ) {
      #pragma unroll
      for (int i = 0; i < 4; ++i) {
        int c = w * 4 + i;
        async16(Kg + (size_t)(kt + 128 + c * 8 + kl8) * CDIM + kswz, &Ks[c * 512]);
        int r7 = ((c & 1) << 2) + vl16;
        async16(Vg + (size_t)(c * 4 + vl16) * TSEQ + kt + 128 + 8 * (vl15 ^ r7),
                &Vs[c * 512]);
      }
      __syncthreads();               // staged data visible (drains vmcnt)
    }
  }

  // ---- epilogue: Y = O / l ----
  #pragma unroll
  for (int j = 0; j < 4; ++j) {
    float rcp = 1.0f / lrun[j];
    #pragma unroll
    for (int nfo = 0; nfo < 4; ++nfo) {
      float val = o[nfo][j] * rcp;
      Y[base + (size_t)(q0 + g * 4 + j) * CDIM + nfo * 16 + f] = f2bf(val);
    }
  }
}

extern "C" void kernel_launch(void* const* d_in, const int* in_sizes, int n_in,
                              void* d_out, int out_size, void* d_ws, size_t ws_size,
                              hipStream_t stream) {
  const float* x  = (const float*)d_in[0];
  const float* cp = (const float*)d_in[1];
  const float* sp = (const float*)d_in[2];
  const float* Wq = (const float*)d_in[3];
  const float* Wk = (const float*)d_in[4];
  const float* Wv = (const float*)d_in[5];
  const float* Wo = (const float*)d_in[6];
  float* out = (float*)d_out;

  const int NX = NBATCH * TSEQ * CDIM;   // 8388608
  const int NW = CDIM * CDIM;            // 1048576

  // ws layout (needs 42 MB): xb/Yb | Vt | Wqb Wkb Wvb Wob
  u16* xb  = (u16*)d_ws;           // also reused as Y after QKV GEMMs
  u16* Vt  = xb + NX;              // [b][h][d][t] transposed V
  u16* Wqb = Vt + NX;
  u16* Wkb = Wqb + NW;
  u16* Wvb = Wkb + NW;
  u16* Wob = Wvb + NW;
  // Q,K live in d_out (2 * 16.8MB bf16 == 33.6MB fp32) until the final GEMM
  u16* Qb = (u16*)d_out;
  u16* Kb = Qb + NX;

  cvt_bf16<<<NX / 1024, 256, 0, stream>>>(x, xb, NX);
  cvt_w4<<<dim3(NW / 1024, 4), 256, 0, stream>>>(Wq, Wk, Wv, Wo, Wqb);

  dim3 gq(NBATCH * TSEQ / 128, 24);           // fused Q|K|V
  gemm_qkv<<<gq, 256, 0, stream>>>(xb, Wqb, Wkb, Wvb, Qb, Kb, Vt);

  rope_rms2<<<dim3(NBATCH * TSEQ * NHEAD / 4, 2), 256, 0, stream>>>(Qb, Kb, cp, sp);

  attn<<<2048, 256, 0, stream>>>(Qb, Kb, Vt, xb);

  dim3 gg(NBATCH * TSEQ / 128, CDIM / 128);   // (64, 8)
  gemm_out<<<gg, 256, 0, stream>>>(xb, Wob, out);
}